// Round 7
// baseline (354.949 us; speedup 1.0000x reference)
//
#include <hip/hip_runtime.h>
#include <hip/hip_bf16.h>

constexpr int B  = 16;
constexpr int C  = 128;
constexpr int H  = 128;
constexpr int W  = 128;
constexpr int CO = 256;
constexpr int HO = 64;
constexpr int WO = 64;

#define EPSV   1e-8f
#define SLOPE  0.2f

typedef short bf16x8 __attribute__((ext_vector_type(8)));
typedef float f32x4  __attribute__((ext_vector_type(4)));

typedef const __attribute__((address_space(1))) unsigned int  gbl_u32;
typedef __attribute__((address_space(3))) unsigned int        lds_u32;

// raw barrier with compiler memory fences (no vmcnt drain, unlike __syncthreads)
__device__ __forceinline__ void bar_raw() {
    asm volatile("" ::: "memory");
    __builtin_amdgcn_s_barrier();
    asm volatile("" ::: "memory");
}
#define WAITV(N) asm volatile("s_waitcnt vmcnt(" #N ")" ::: "memory")

__device__ __forceinline__ short f2bs(float v) {
    __hip_bfloat16 h = __float2bfloat16(v);
    return *(short*)&h;
}
__device__ __forceinline__ float bs2f(short s) {
    __hip_bfloat16 h = *(__hip_bfloat16*)&s;
    return __bfloat162float(h);
}

// ---------------------------------------------------------------------------
// demod: d[conv][b][o] = rsqrt(sum_{i,k}(w[o,i,k]*(s[b,i]+1))^2 + eps)
// ---------------------------------------------------------------------------
__global__ __launch_bounds__(128) void demod_kernel(
    const float* __restrict__ w1, const float* __restrict__ w2,
    const float* __restrict__ s1, const float* __restrict__ s2,
    float* __restrict__ d)
{
    int bid  = blockIdx.x;          // conv*2048 + b*128 + o
    int conv = bid >> 11;
    int b    = (bid >> 7) & 15;
    int o    = bid & 127;
    const float* w = conv ? w2 : w1;
    const float* s = conv ? s2 : s1;
    int i = threadIdx.x;
    float sv = s[b * C + i] + 1.0f;
    const float* wp = w + (o * C + i) * 9;
    float sum = 0.f;
    #pragma unroll
    for (int k = 0; k < 9; ++k) { float t = wp[k] * sv; sum += t * t; }
    #pragma unroll
    for (int off = 32; off; off >>= 1) sum += __shfl_down(sum, off);
    __shared__ float red[2];
    if ((threadIdx.x & 63) == 0) red[threadIdx.x >> 6] = sum;
    __syncthreads();
    if (threadIdx.x == 0) d[bid] = rsqrtf(red[0] + red[1] + EPSV);
}

// ---------------------------------------------------------------------------
// expand -> stage/step-major weight tiling for LDS staging.
// wm[cb][icH=ic>>6][step=tap*2+icL][ocT=oc>>4][frag 512]
// In-fragment (verified conflict-free ds_read_b128):
//   frag[((ic>>3)&3)*128 + (oc&15)*8 + (ic&7)]
// ---------------------------------------------------------------------------
__global__ __launch_bounds__(256) void expand_kernel(
    const float* __restrict__ w1, const float* __restrict__ w2,
    const float* __restrict__ s1, const float* __restrict__ s2,
    const float* __restrict__ d, short* __restrict__ wm)
{
    int idx = blockIdx.x * 256 + threadIdx.x;
    int ic  = idx & 127;
    int oc  = (idx >> 7) & 127;
    int t   = idx >> 14;            // cb*9+tap, < 288
    int tap = t % 9;
    int cb  = t / 9;                // conv*16+b
    int b   = cb & 15;
    int conv= cb >> 4;
    const float* w = conv ? w2 : w1;
    const float* s = conv ? s2 : s1;
    float v = w[(oc * C + ic) * 9 + tap] * (s[b * C + ic] + 1.0f)
            * d[(conv * B + b) * C + oc];
    int icH = ic >> 6, icL = (ic >> 5) & 1;
    int dst = cb * 147456
            + ((icH * 18 + tap * 2 + icL) * 8 + (oc >> 4)) * 512
            + ((ic >> 3) & 3) * 128 + (oc & 15) * 8 + (ic & 7);
    wm[dst] = f2bs(v);
}

// ---------------------------------------------------------------------------
// dwexpand: dwm[step=(ic>>5)*16+tap][ocH=oc>>7][ocT7=(oc>>4)&7][frag 512]
// ---------------------------------------------------------------------------
__global__ __launch_bounds__(256) void dwexpand_kernel(
    const float* __restrict__ dw, short* __restrict__ dwm)
{
    int idx = blockIdx.x * 256 + threadIdx.x;   // 16*256*128 = 524288
    int ic  = idx & 127;
    int oc  = (idx >> 7) & 255;
    int tap = idx >> 15;
    int dst = ((ic >> 5) * 16 + tap) * 8192 + (oc >> 7) * 4096
            + ((oc >> 4) & 7) * 512
            + ((ic >> 3) & 3) * 128 + (oc & 15) * 8 + (ic & 7);
    dwm[dst] = f2bs(dw[(oc * C + ic) * 16 + tap]);
}

// ---------------------------------------------------------------------------
// nchw(f32) -> nhwc(bf16) transpose of features.
// ---------------------------------------------------------------------------
__global__ __launch_bounds__(256) void nchw2nhwc_kernel(
    const float* __restrict__ in, short* __restrict__ out)
{
    __shared__ short s[128 * 136];
    int bid = blockIdx.x;                   // b*128 + h
    int h = bid & 127, b = bid >> 7;
    int tid = threadIdx.x;
    for (int i = tid; i < 128 * 32; i += 256) {
        int w4 = i & 31, ic = i >> 5;
        float4 v = *(const float4*)&in[((b * C + ic) * H + h) * W + w4 * 4];
        s[(w4 * 4 + 0) * 136 + ic] = f2bs(v.x);
        s[(w4 * 4 + 1) * 136 + ic] = f2bs(v.y);
        s[(w4 * 4 + 2) * 136 + ic] = f2bs(v.z);
        s[(w4 * 4 + 3) * 136 + ic] = f2bs(v.w);
    }
    __syncthreads();
    for (int i = tid; i < 128 * 16; i += 256) {
        int icg = i & 15, w = i >> 4;
        *(uint4*)&out[((b * H + h) * W + w) * C + icg * 8] =
            *(uint4*)&s[w * 136 + icg * 8];
    }
}

// ---------------------------------------------------------------------------
// conv3x3 MFMA v7 — v6 schedule + slot-major sIn (all LDS traffic is the
// verified 256B-contiguous-per-quarter-wave pattern; zero conflicts).
// sIn[slot 8][pix 180][8 ic]: read addr = slot*1440 + pix*8 shorts, lane
// l15 inside pix -> 16 lanes span 256 contiguous B. Same for writes.
// block: 128 px (8h x 16w) x 128 oc; LDS 23,040+24,576 = 47,616 -> 3 blk/CU.
// ---------------------------------------------------------------------------
__global__ __launch_bounds__(256, 3) void conv3x3_mfma(
    const short* __restrict__ in, const short* __restrict__ wmc,
    const short* __restrict__ res, short* __restrict__ out)
{
    __shared__ short sW[3][4096];       // 24,576 B
    __shared__ short sIn[8 * 180 * 8];  // 23,040 B  [slot][pix][8]

    int bid = blockIdx.x;
    int wt = bid & 7, ht = (bid >> 3) & 15, b = bid >> 7;
    int w0 = wt * 16, h0 = ht * 8;
    int tid  = threadIdx.x;
    int lane = tid & 63, wv = tid >> 6;
    int q = lane >> 4, l15 = lane & 15;
    int wr = wv & 1;       // row half
    int wc = wv >> 1;      // oc half

    const short* wb = wmc + b * 147456;

    auto stageIn = [&](int st) {       // 64-ic half `st` of the 10x18 halo
        for (int i = tid; i < 1536; i += 256) {
            int p16 = i & 15, slot = (i >> 4) & 7, ph = i >> 7;
            int pix = ph * 16 + p16;
            if (pix < 180) {
                int hl = pix / 18, wl = pix - hl * 18;
                int gh = h0 - 1 + hl, gw = w0 - 1 + wl;
                uint4 v = make_uint4(0u, 0u, 0u, 0u);
                if ((unsigned)gh < (unsigned)H && (unsigned)gw < (unsigned)W)
                    v = *(const uint4*)&in[((b * H + gh) * W + gw) * C
                                           + st * 64 + slot * 8];
                *(uint4*)&sIn[(slot * 180 + pix) * 8] = v;
            }
        }
    };
    auto stageW = [&](int s) {         // global step s -> sW[s%3] (8 KB)
        #pragma unroll
        for (int i = 0; i < 2; ++i) {
            const short* g = wb + (s / 18) * 73728 + (s % 18) * 4096
                           + (wv * 2 + i) * 512 + lane * 8;
            __builtin_amdgcn_global_load_lds(
                (gbl_u32*)g, (lds_u32*)&sW[s % 3][(wv * 2 + i) * 512], 16, 0, 0);
        }
    };

    f32x4 acc[4][4];
    #pragma unroll
    for (int mt = 0; mt < 4; ++mt)
        #pragma unroll
        for (int nt = 0; nt < 4; ++nt)
            acc[mt][nt] = (f32x4){0.f, 0.f, 0.f, 0.f};

    stageW(0); stageW(1); stageIn(0);
    __syncthreads();

    const int abase = wr * (4 * 18 * 8) + l15 * 8;   // + q*1440 + imm
    const int bbase = q * 128 + l15 * 8;

    #pragma unroll
    for (int s = 0; s < 36; ++s) {
        if (s == 18) {                 // input half boundary
            bar_raw();                 // all reads of half 0 complete
            stageIn(1);
            __syncthreads();           // half-1 visible (drains stage 18,19 too)
        } else {
            if (s == 35) { WAITV(0); } else { WAITV(2); }
            bar_raw();                 // sW[s%3] landed for all waves;
        }                              // readers of sW[(s+2)%3] done (step s-1)
        if (s + 2 < 36) stageW(s + 2);
        const int loc = s % 18, tap = loc >> 1, icL = loc & 1;
        const int dh = tap / 3, dwd = tap - dh * 3;
        bf16x8 af[4], bf[4];
        #pragma unroll
        for (int mt = 0; mt < 4; ++mt)
            af[mt] = *(const bf16x8*)&sIn[abase + q * 1440 + icL * 5760
                                          + ((mt + dh) * 18 + dwd) * 8];
        #pragma unroll
        for (int nt = 0; nt < 4; ++nt)
            bf[nt] = *(const bf16x8*)&sW[s % 3][(wc * 4 + nt) * 512 + bbase];
        #pragma unroll
        for (int mt = 0; mt < 4; ++mt)
            #pragma unroll
            for (int nt = 0; nt < 4; ++nt)
                acc[mt][nt] = __builtin_amdgcn_mfma_f32_16x16x32_bf16(
                    af[mt], bf[nt], acc[mt][nt], 0, 0, 0);
    }

    bool has_res = (res != nullptr);
    #pragma unroll
    for (int mt = 0; mt < 4; ++mt) {
        int h = h0 + wr * 4 + mt;
        #pragma unroll
        for (int nt = 0; nt < 4; ++nt) {
            int oc = wc * 64 + nt * 16 + l15;
            #pragma unroll
            for (int reg = 0; reg < 4; ++reg) {
                int w = w0 + q * 4 + reg;
                int idx = ((b * H + h) * W + w) * C + oc;
                float v = acc[mt][nt][reg];
                if (has_res) v += bs2f(res[idx]);
                v = v >= 0.f ? v : SLOPE * v;
                out[idx] = f2bs(v);
            }
        }
    }
}

// ---------------------------------------------------------------------------
// downconv MFMA v6 — v5 schedule + slot-major sIn (verified-contiguous LDS).
// sIn[slot 4][ppix 612][8 ic], ppix = par*306 + ihl*17 + col (parity-split
// stride-2 deinterleave). Read: lane (q,l15) -> q*4896 + (imm + l15)*8
// shorts -> 256B contiguous per quarter. Writes pixel-minor: same pattern.
// block: 8oh x 16ow x 128 oc; LDS 39,168+24,576 = 63,744 -> 2 blocks/CU.
// K = 64 steps, 3-buf sW, one barrier/step, DMA depth-2, counted vmcnt.
// ---------------------------------------------------------------------------
__global__ __launch_bounds__(256, 2) void downconv_mfma(
    const short* __restrict__ in, const short* __restrict__ dwm,
    const float* __restrict__ db, float* __restrict__ out)
{
    __shared__ short sW[3][4096];        // 24,576 B
    __shared__ short sIn[4 * 612 * 8];   // 39,168 B  [slot][ppix][8]

    int bid = blockIdx.x;
    int wt = bid & 3;
    int ht = (bid >> 2) & 7;
    int ot = (bid >> 5) & 1;
    int b  = bid >> 6;
    int ow0 = wt * 16, oh0 = ht * 8, oc0 = ot * 128;
    int ih0 = 2 * oh0 - 1, iw0 = 2 * ow0 - 1;

    int tid  = threadIdx.x;
    int lane = tid & 63, wv = tid >> 6;
    int q = lane >> 4, l15 = lane & 15;

    const short* wbase = dwm + ot * 4096;

    auto stageIn = [&](int icC) {      // one 32-ic chunk of the 18x34 halo
        for (int i = tid; i < 2496; i += 256) {
            int p16 = i & 15, slot = (i >> 4) & 3, ph = i >> 6;
            int pix = ph * 16 + p16;             // plane-order ppix
            if (pix < 612) {
                int par = 0, rem = pix;
                if (rem >= 306) { par = 1; rem -= 306; }
                int ihl = rem / 17, col = rem - ihl * 17;
                int gh = ih0 + ihl, gw = iw0 + 2 * col + par;
                uint4 v = make_uint4(0u, 0u, 0u, 0u);
                if ((unsigned)gh < (unsigned)H && (unsigned)gw < (unsigned)W)
                    v = *(const uint4*)&in[((b * H + gh) * W + gw) * C
                                           + icC * 32 + slot * 8];
                *(uint4*)&sIn[(slot * 612 + pix) * 8] = v;
            }
        }
    };
    auto stageW = [&](int s) {         // global step s -> sW[s%3] (8 KB)
        #pragma unroll
        for (int j = 0; j < 2; ++j) {
            const short* g = wbase + s * 8192 + (wv * 2 + j) * 512 + lane * 8;
            __builtin_amdgcn_global_load_lds(
                (gbl_u32*)g, (lds_u32*)&sW[s % 3][(wv * 2 + j) * 512], 16, 0, 0);
        }
    };

    f32x4 acc[2][8];
    #pragma unroll
    for (int mt = 0; mt < 2; ++mt)
        #pragma unroll
        for (int nt = 0; nt < 8; ++nt)
            acc[mt][nt] = (f32x4){0.f, 0.f, 0.f, 0.f};

    stageW(0); stageW(1); stageIn(0);
    __syncthreads();

    const int abase = q * 128 + l15 * 8;         // weight frag base (shorts)
    const int pbase = l15 * 8;                   // + q*4896 + imm*8

    #pragma unroll
    for (int s = 0; s < 64; ++s) {
        if (s > 0 && (s & 15) == 0) {            // ic-chunk boundary: 16,32,48
            bar_raw();                           // all reads of old chunk done
            stageIn(s >> 4);
            __syncthreads();
        } else {
            if (s == 63) { WAITV(0); } else { WAITV(2); }
            bar_raw();
        }
        if (s + 2 < 64) stageW(s + 2);
        const int tap = s & 15;
        const int dh = tap >> 2, dwn = tap & 3;
        const int par = dwn & 1, cb0 = dwn >> 1;
        bf16x8 af[2], bf[8];
        #pragma unroll
        for (int mt = 0; mt < 2; ++mt)
            af[mt] = *(const bf16x8*)&sW[s % 3][(wv * 2 + mt) * 512 + abase];
        #pragma unroll
        for (int nt = 0; nt < 8; ++nt)
            bf[nt] = *(const bf16x8*)&sIn[q * 4896 + pbase
                                          + (par * 306 + (2 * nt + dh) * 17 + cb0) * 8];
        #pragma unroll
        for (int mt = 0; mt < 2; ++mt)
            #pragma unroll
            for (int nt = 0; nt < 8; ++nt)
                acc[mt][nt] = __builtin_amdgcn_mfma_f32_16x16x32_bf16(
                    af[mt], bf[nt], acc[mt][nt], 0, 0, 0);
    }

    // epilogue
    #pragma unroll
    for (int mt = 0; mt < 2; ++mt) {
        f32x4 bi = *(const f32x4*)&db[oc0 + (wv * 2 + mt) * 16 + q * 4];
        #pragma unroll
        for (int nt = 0; nt < 8; ++nt) {
            int oh = oh0 + nt;
            #pragma unroll
            for (int reg = 0; reg < 4; ++reg) {
                int oc = oc0 + (wv * 2 + mt) * 16 + q * 4 + reg;
                out[((b * CO + oc) * HO + oh) * WO + ow0 + l15] =
                    acc[mt][nt][reg] + bi[reg];
            }
        }
    }
}

// ---------------------------------------------------------------------------
extern "C" void kernel_launch(void* const* d_in, const int* in_sizes, int n_in,
                              void* d_out, int out_size, void* d_ws, size_t ws_size,
                              hipStream_t stream) {
    const float* features = (const float*)d_in[0];
    const float* sm1      = (const float*)d_in[1];   // style_mean1 -> s1
    const float* ss1      = (const float*)d_in[2];   // style_std1  -> s2 (per reference)
    const float* w1       = (const float*)d_in[6];
    const float* w2       = (const float*)d_in[7];
    const float* dw       = (const float*)d_in[8];
    const float* db       = (const float*)d_in[9];
    float* out = (float*)d_out;

    char* ws = (char*)d_ws;
    short* x1  = (short*)ws;                              // 67,108,864 B
    short* x2  = (short*)(ws + 67108864);                 // 67,108,864 B (also fx)
    short* wm  = (short*)(ws + 134217728);                // 9,437,184 B
    short* dwm = (short*)(ws + 143654912);                // 1,048,576 B
    float* dv  = (float*)(ws + 144703488);                // 16,384 B

    demod_kernel    <<<4096, 128, 0, stream>>>(w1, w2, sm1, ss1, dv);
    expand_kernel   <<<18432, 256, 0, stream>>>(w1, w2, sm1, ss1, dv, wm);
    dwexpand_kernel <<<2048, 256, 0, stream>>>(dw, dwm);
    nchw2nhwc_kernel<<<2048, 256, 0, stream>>>(features, x2);
    conv3x3_mfma    <<<2048, 256, 0, stream>>>(x2, wm, nullptr, x1);
    conv3x3_mfma    <<<2048, 256, 0, stream>>>(x1, wm + 16 * 147456, x1, x2);
    downconv_mfma   <<<1024, 256, 0, stream>>>(x2, dwm, db, out);
}

// Round 9
// 317.045 us; speedup vs baseline: 1.1196x; 1.1196x over previous
//
#include <hip/hip_runtime.h>
#include <hip/hip_bf16.h>

constexpr int B  = 16;
constexpr int C  = 128;
constexpr int H  = 128;
constexpr int W  = 128;
constexpr int CO = 256;
constexpr int HO = 64;
constexpr int WO = 64;

#define EPSV   1e-8f
#define SLOPE  0.2f

typedef short bf16x8 __attribute__((ext_vector_type(8)));
typedef float f32x4  __attribute__((ext_vector_type(4)));

typedef const __attribute__((address_space(1))) unsigned int  gbl_u32;
typedef __attribute__((address_space(3))) unsigned int        lds_u32;

// raw barrier with compiler memory fences (no vmcnt drain, unlike __syncthreads)
__device__ __forceinline__ void bar_raw() {
    asm volatile("" ::: "memory");
    __builtin_amdgcn_s_barrier();
    asm volatile("" ::: "memory");
}
#define WAITV(N) asm volatile("s_waitcnt vmcnt(" #N ")" ::: "memory")

__device__ __forceinline__ short f2bs(float v) {
    __hip_bfloat16 h = __float2bfloat16(v);
    return *(short*)&h;
}
__device__ __forceinline__ float bs2f(short s) {
    __hip_bfloat16 h = *(__hip_bfloat16*)&s;
    return __bfloat162float(h);
}

// ---------------------------------------------------------------------------
// demod: d[conv][b][o] = rsqrt(sum_{i,k}(w[o,i,k]*(s[b,i]+1))^2 + eps)
// ---------------------------------------------------------------------------
__global__ __launch_bounds__(128) void demod_kernel(
    const float* __restrict__ w1, const float* __restrict__ w2,
    const float* __restrict__ s1, const float* __restrict__ s2,
    float* __restrict__ d)
{
    int bid  = blockIdx.x;          // conv*2048 + b*128 + o
    int conv = bid >> 11;
    int b    = (bid >> 7) & 15;
    int o    = bid & 127;
    const float* w = conv ? w2 : w1;
    const float* s = conv ? s2 : s1;
    int i = threadIdx.x;
    float sv = s[b * C + i] + 1.0f;
    const float* wp = w + (o * C + i) * 9;
    float sum = 0.f;
    #pragma unroll
    for (int k = 0; k < 9; ++k) { float t = wp[k] * sv; sum += t * t; }
    #pragma unroll
    for (int off = 32; off; off >>= 1) sum += __shfl_down(sum, off);
    __shared__ float red[2];
    if ((threadIdx.x & 63) == 0) red[threadIdx.x >> 6] = sum;
    __syncthreads();
    if (threadIdx.x == 0) d[bid] = rsqrtf(red[0] + red[1] + EPSV);
}

// ---------------------------------------------------------------------------
// expand -> stage/step-major weight tiling for LDS staging (r5-verified).
// wm[cb][icH=ic>>6][step=tap*2+icL][ocT=oc>>4][frag 512]
// In-fragment (measured 0-conflict ds_read_b128):
//   frag[((ic>>3)&3)*128 + (oc&15)*8 + (ic&7)]
// ---------------------------------------------------------------------------
__global__ __launch_bounds__(256) void expand_kernel(
    const float* __restrict__ w1, const float* __restrict__ w2,
    const float* __restrict__ s1, const float* __restrict__ s2,
    const float* __restrict__ d, short* __restrict__ wm)
{
    int idx = blockIdx.x * 256 + threadIdx.x;
    int ic  = idx & 127;
    int oc  = (idx >> 7) & 127;
    int t   = idx >> 14;            // cb*9+tap, < 288
    int tap = t % 9;
    int cb  = t / 9;                // conv*16+b
    int b   = cb & 15;
    int conv= cb >> 4;
    const float* w = conv ? w2 : w1;
    const float* s = conv ? s2 : s1;
    float v = w[(oc * C + ic) * 9 + tap] * (s[b * C + ic] + 1.0f)
            * d[(conv * B + b) * C + oc];
    int icH = ic >> 6, icL = (ic >> 5) & 1;
    int dst = cb * 147456
            + ((icH * 18 + tap * 2 + icL) * 8 + (oc >> 4)) * 512
            + ((ic >> 3) & 3) * 128 + (oc & 15) * 8 + (ic & 7);
    wm[dst] = f2bs(v);
}

// ---------------------------------------------------------------------------
// dwexpand: dwm[step=(ic>>5)*16+tap][ocT=oc>>4 (16, flat)][frag 512]
// (flat ocT*512 is identical to r5's (oc>>7)*4096+((oc>>4)&7)*512)
// ---------------------------------------------------------------------------
__global__ __launch_bounds__(256) void dwexpand_kernel(
    const float* __restrict__ dw, short* __restrict__ dwm)
{
    int idx = blockIdx.x * 256 + threadIdx.x;   // 16*256*128 = 524288
    int ic  = idx & 127;
    int oc  = (idx >> 7) & 255;
    int tap = idx >> 15;
    int dst = ((ic >> 5) * 16 + tap) * 8192 + (oc >> 4) * 512
            + ((ic >> 3) & 3) * 128 + (oc & 15) * 8 + (ic & 7);
    dwm[dst] = f2bs(dw[(oc * C + ic) * 16 + tap]);
}

// ---------------------------------------------------------------------------
// nchw(f32) -> nhwc(bf16) transpose of features.
// ---------------------------------------------------------------------------
__global__ __launch_bounds__(256) void nchw2nhwc_kernel(
    const float* __restrict__ in, short* __restrict__ out)
{
    __shared__ short s[128 * 136];
    int bid = blockIdx.x;                   // b*128 + h
    int h = bid & 127, b = bid >> 7;
    int tid = threadIdx.x;
    for (int i = tid; i < 128 * 32; i += 256) {
        int w4 = i & 31, ic = i >> 5;
        float4 v = *(const float4*)&in[((b * C + ic) * H + h) * W + w4 * 4];
        s[(w4 * 4 + 0) * 136 + ic] = f2bs(v.x);
        s[(w4 * 4 + 1) * 136 + ic] = f2bs(v.y);
        s[(w4 * 4 + 2) * 136 + ic] = f2bs(v.z);
        s[(w4 * 4 + 3) * 136 + ic] = f2bs(v.w);
    }
    __syncthreads();
    for (int i = tid; i < 128 * 16; i += 256) {
        int icg = i & 15, w = i >> 4;
        *(uint4*)&out[((b * H + h) * W + w) * C + icg * 8] =
            *(uint4*)&s[w * 136 + icg * 8];
    }
}

// ---------------------------------------------------------------------------
// conv3x3 MFMA — EXACT r5 (327 us PASSING) version. counted-vmcnt pipeline.
// block: 128 px (8h x 16w) x 128 oc; LDS 39,424 B -> 4 blocks/CU.
// ---------------------------------------------------------------------------
__global__ __launch_bounds__(256, 4) void conv3x3_mfma(
    const short* __restrict__ in, const short* __restrict__ wmc,
    const short* __restrict__ res, short* __restrict__ out)
{
    __shared__ short sIn[180 * 64];     // 23,040 B
    __shared__ short sW[2][4096];       // 16,384 B

    int bid = blockIdx.x;
    int wt = bid & 7, ht = (bid >> 3) & 15, b = bid >> 7;
    int w0 = wt * 16, h0 = ht * 8;
    int tid  = threadIdx.x;
    int lane = tid & 63, wv = tid >> 6;
    int q = lane >> 4, l15 = lane & 15;
    int wr = wv & 1;       // row half
    int wc = wv >> 1;      // oc half

    const short* wb = wmc + b * 147456;

    auto stageIn = [&](int st) {       // stage 64-ic half `st` of the halo
        for (int i = tid; i < 180 * 8; i += 256) {
            int slot = i & 7, pix = i >> 3;
            int hl = pix / 18, wl = pix - hl * 18;
            int gh = h0 - 1 + hl, gw = w0 - 1 + wl;
            uint4 v = make_uint4(0u, 0u, 0u, 0u);
            if ((unsigned)gh < (unsigned)H && (unsigned)gw < (unsigned)W)
                v = *(const uint4*)&in[((b * H + gh) * W + gw) * C + st * 64 + slot * 8];
            *(uint4*)&sIn[pix * 64 + ((slot ^ (pix & 7)) << 3)] = v;
        }
    };
    auto stageW = [&](int st, int s, int buf) {   // 8 KB step -> sW[buf]
        #pragma unroll
        for (int i = 0; i < 2; ++i) {
            const short* g = wb + st * 73728 + s * 4096
                           + (wv * 2 + i) * 512 + lane * 8;
            __builtin_amdgcn_global_load_lds(
                (gbl_u32*)g, (lds_u32*)&sW[buf][(wv * 2 + i) * 512], 16, 0, 0);
        }
    };

    f32x4 acc[4][4];
    #pragma unroll
    for (int mt = 0; mt < 4; ++mt)
        #pragma unroll
        for (int nt = 0; nt < 4; ++nt)
            acc[mt][nt] = (f32x4){0.f, 0.f, 0.f, 0.f};

    stageW(0, 0, 0);
    stageIn(0);
    __syncthreads();          // full drain once: L(0) + input half 0 landed

    int bfbase = q * 128 + l15 * 8;   // conflict-free fragment read

    #pragma unroll 1
    for (int st = 0; st < 2; ++st) {
        #pragma unroll 2
        for (int s = 0; s < 18; ++s) {
            int tap = s >> 1, icL = s & 1;
            int dh = tap / 3, dwd = tap - dh * 3;
            // issue next step's weights (WAR-safe: prior step's E barrier passed)
            if (s < 17)        stageW(st, s + 1, (s + 1) & 1);
            else if (st == 0)  stageW(1, 0, 0);
            // RAW: my step-s loads done (2 newest = step s+1 stay in flight)
            if (st == 1 && s == 17) { WAITV(0); } else { WAITV(2); }
            bar_raw();                       // everyone's step-s weights landed
            // fragments
            bf16x8 af[4], bf[4];
            #pragma unroll
            for (int mt = 0; mt < 4; ++mt) {
                int pix  = (wr * 4 + mt + dh) * 18 + l15 + dwd;
                int slot = (icL * 4 + q) ^ (pix & 7);
                af[mt] = *(const bf16x8*)&sIn[pix * 64 + slot * 8];
            }
            #pragma unroll
            for (int nt = 0; nt < 4; ++nt)
                bf[nt] = *(const bf16x8*)&sW[s & 1][(wc * 4 + nt) * 512 + bfbase];
            // compute
            #pragma unroll
            for (int mt = 0; mt < 4; ++mt)
                #pragma unroll
                for (int nt = 0; nt < 4; ++nt)
                    acc[mt][nt] = __builtin_amdgcn_mfma_f32_16x16x32_bf16(
                        af[mt], bf[nt], acc[mt][nt], 0, 0, 0);
            bar_raw();                       // all reads of sW[s&1] complete
        }
        if (st == 0) { stageIn(1); __syncthreads(); }
    }

    bool has_res = (res != nullptr);
    #pragma unroll
    for (int mt = 0; mt < 4; ++mt) {
        int h = h0 + wr * 4 + mt;
        #pragma unroll
        for (int nt = 0; nt < 4; ++nt) {
            int oc = wc * 64 + nt * 16 + l15;
            #pragma unroll
            for (int reg = 0; reg < 4; ++reg) {
                int w = w0 + q * 4 + reg;
                int idx = ((b * H + h) * W + w) * C + oc;
                float v = acc[mt][nt][reg];
                if (has_res) v += bs2f(res[idx]);
                v = v >= 0.f ? v : SLOPE * v;
                out[idx] = f2bs(v);
            }
        }
    }
}

// ---------------------------------------------------------------------------
// downconv MFMA v8 — r5 schedule skeleton, widened wave tile ONLY.
// block: 8oh x 16ow x ALL 256 oc (grid 512); 4 waves, each 4 ocT x 128 px
// -> 12 ds_read_b128 per 32 MFMA (was 10 per 16): LDS reads/MFMA -40%,
// weight DMA halved (each 16KB step feeds 128 MFMAs/block, was 64).
// sIn: r5 layout/indexing byte-identical. sW: 2 x 16KB, 4 DMAs/step,
// WAITV(4); absolute-step stageW (step+1 rolls into next chunk's step 0,
// drained by the boundary __syncthreads, exactly like r5's rollover).
// LDS 39,168 + 32,768 = 71,936 B -> 2 blocks/CU (r5 also ran 2).
// ---------------------------------------------------------------------------
__global__ __launch_bounds__(256, 2) void downconv_mfma(
    const short* __restrict__ in, const short* __restrict__ dwm,
    const float* __restrict__ db, float* __restrict__ out)
{
    __shared__ short sIn[2 * 306 * 32];   // 39,168 B
    __shared__ short sW[2][8192];         // 32,768 B

    int bid = blockIdx.x;
    int wt = bid & 3;
    int ht = (bid >> 2) & 7;
    int b  = bid >> 5;
    int ow0 = wt * 16, oh0 = ht * 8;
    int ih0 = 2 * oh0 - 1, iw0 = 2 * ow0 - 1;

    int tid  = threadIdx.x;
    int lane = tid & 63, wv = tid >> 6;   // wv = oc quarter
    int q = lane >> 4, l15 = lane & 15;

    auto stageIn = [&](int icC) {      // one 32-ic chunk of the 18x34 halo
        for (int i = tid; i < 612 * 4; i += 256) {
            int slot = i & 3, pix = i >> 2;
            int ihl = pix / 34, iwl = pix - ihl * 34;
            int gh = ih0 + ihl, gw = iw0 + iwl;
            uint4 v = make_uint4(0u, 0u, 0u, 0u);
            if ((unsigned)gh < (unsigned)H && (unsigned)gw < (unsigned)W)
                v = *(const uint4*)&in[((b * H + gh) * W + gw) * C + icC * 32 + slot * 8];
            int par = iwl & 1, pl = ihl * 17 + (iwl >> 1);
            *(uint4*)&sIn[(par * 306 + pl) * 32 + ((slot ^ ((pl >> 1) & 3)) << 3)] = v;
        }
    };
    auto stageW = [&](int s) {         // 16 KB step s -> sW[s&1] (all 16 ocT)
        #pragma unroll
        for (int j = 0; j < 4; ++j) {
            int base = (j * 4 + wv) * 512;
            const short* g = dwm + s * 8192 + base + lane * 8;
            __builtin_amdgcn_global_load_lds(
                (gbl_u32*)g, (lds_u32*)&sW[s & 1][base], 16, 0, 0);
        }
    };

    f32x4 acc[4][8];
    #pragma unroll
    for (int mt = 0; mt < 4; ++mt)
        #pragma unroll
        for (int nt = 0; nt < 8; ++nt)
            acc[mt][nt] = (f32x4){0.f, 0.f, 0.f, 0.f};

    stageW(0);
    stageIn(0);
    __syncthreads();

    const int abase = q * 128 + l15 * 8;   // conflict-free fragment read

    #pragma unroll 1
    for (int icC = 0; icC < 4; ++icC) {
        #pragma unroll 2
        for (int tap = 0; tap < 16; ++tap) {
            int step = icC * 16 + tap;
            if (step < 63) stageW(step + 1);   // step+1==next chunk's 0 at tap 15
            if (step < 63) { WAITV(4); } else { WAITV(0); }
            bar_raw();                 // step's weights landed (all threads)
            const int dh = tap >> 2, dwn = tap & 3;
            const int par = dwn & 1, cb0 = dwn >> 1;
            bf16x8 af[4], bf[8];
            #pragma unroll
            for (int mt = 0; mt < 4; ++mt)
                af[mt] = *(const bf16x8*)&sW[tap & 1][(wv * 4 + mt) * 512 + abase];
            #pragma unroll
            for (int nt = 0; nt < 8; ++nt) {
                int pl = (2 * nt + dh) * 17 + cb0 + l15;
                bf[nt] = *(const bf16x8*)&sIn[(par * 306 + pl) * 32
                                              + ((q ^ ((pl >> 1) & 3)) << 3)];
            }
            #pragma unroll
            for (int mt = 0; mt < 4; ++mt)
                #pragma unroll
                for (int nt = 0; nt < 8; ++nt)
                    acc[mt][nt] = __builtin_amdgcn_mfma_f32_16x16x32_bf16(
                        af[mt], bf[nt], acc[mt][nt], 0, 0, 0);
            bar_raw();                 // all reads of sW[tap&1] complete
        }
        if (icC < 3) { stageIn(icC + 1); __syncthreads(); }
    }

    // epilogue: D row (q*4+reg) = oc within ocT, col (l15) = ow, nt = oh
    #pragma unroll
    for (int mt = 0; mt < 4; ++mt) {
        f32x4 bi = *(const f32x4*)&db[(wv * 4 + mt) * 16 + q * 4];
        #pragma unroll
        for (int nt = 0; nt < 8; ++nt) {
            int oh = oh0 + nt;
            #pragma unroll
            for (int reg = 0; reg < 4; ++reg) {
                int oc = (wv * 4 + mt) * 16 + q * 4 + reg;
                out[((b * CO + oc) * HO + oh) * WO + ow0 + l15] =
                    acc[mt][nt][reg] + bi[reg];
            }
        }
    }
}

// ---------------------------------------------------------------------------
extern "C" void kernel_launch(void* const* d_in, const int* in_sizes, int n_in,
                              void* d_out, int out_size, void* d_ws, size_t ws_size,
                              hipStream_t stream) {
    const float* features = (const float*)d_in[0];
    const float* sm1      = (const float*)d_in[1];   // style_mean1 -> s1
    const float* ss1      = (const float*)d_in[2];   // style_std1  -> s2 (per reference)
    const float* w1       = (const float*)d_in[6];
    const float* w2       = (const float*)d_in[7];
    const float* dw       = (const float*)d_in[8];
    const float* db       = (const float*)d_in[9];
    float* out = (float*)d_out;

    char* ws = (char*)d_ws;
    short* x1  = (short*)ws;                              // 67,108,864 B
    short* x2  = (short*)(ws + 67108864);                 // 67,108,864 B (also fx)
    short* wm  = (short*)(ws + 134217728);                // 9,437,184 B
    short* dwm = (short*)(ws + 143654912);                // 1,048,576 B
    float* dv  = (float*)(ws + 144703488);                // 16,384 B

    demod_kernel    <<<4096, 128, 0, stream>>>(w1, w2, sm1, ss1, dv);
    expand_kernel   <<<18432, 256, 0, stream>>>(w1, w2, sm1, ss1, dv, wm);
    dwexpand_kernel <<<2048, 256, 0, stream>>>(dw, dwm);
    nchw2nhwc_kernel<<<2048, 256, 0, stream>>>(features, x2);
    conv3x3_mfma    <<<2048, 256, 0, stream>>>(x2, wm, nullptr, x1);
    conv3x3_mfma    <<<2048, 256, 0, stream>>>(x1, wm + 16 * 147456, x1, x2);
    downconv_mfma   <<<512, 256, 0, stream>>>(x2, dwm, db, out);
}